// Round 9
// baseline (161.892 us; speedup 1.0000x reference)
//
#include <hip/hip_runtime.h>
#include <stdint.h>

// ---------------------------------------------------------------------------
// VarianceMaximizationCovarianceMinimizationLoss on MI355X
//   features [65536,2,256] fp32, labels [65536] int32 -> scalar fp32 loss
// Round 9: TLP instead of ILP. 4-way column split -> grid 540 (~2.1 WG/CU),
//   acc=32 regs, single-buffer 32KB LDS + 4KB idx-in-LDS (36KB -> 4 WG/CU
//   possible). No prefetch pipeline, no sched_barrier: co-resident WGs hide
//   each other's gather latency. (Rounds 6-8: compiler sank every prefetch;
//   VGPR stayed ~104-108. Occupancy 18% with grid 270 was the real cap.)
// ---------------------------------------------------------------------------

#define NCLS  8
#define D     256
#define CHUNK 1024
#define SEG   256
#define EPSF  1e-4f
// sum_c ceil(n_c/CHUNK) <= nrows/CHUNK + NCLS-1 = 128+7 = 135
#define TMAX  144

typedef __bf16 bf16x8 __attribute__((ext_vector_type(8)));
typedef float  f32x4  __attribute__((ext_vector_type(4)));

__device__ __forceinline__ unsigned short f2bf(float f) {
    unsigned int x = __float_as_uint(f);
    x += 0x7fffu + ((x >> 16) & 1u);      // round-to-nearest-even
    return (unsigned short)(x >> 16);
}

// ---- k1a: histogram of row counts per class -------------------------------
__global__ void k_hist(const int* __restrict__ labels, int nlab, int vfac,
                       int* __restrict__ counts) {
    __shared__ int lc[NCLS];
    int t = threadIdx.x;
    if (t < NCLS) lc[t] = 0;
    __syncthreads();
    for (int i = blockIdx.x * blockDim.x + t; i < nlab; i += gridDim.x * blockDim.x)
        atomicAdd(&lc[labels[i] & 7], vfac);
    __syncthreads();
    if (t < NCLS && lc[t]) atomicAdd(&counts[t], lc[t]);
}

// ---- k1b: offsets + cursors ----------------------------------------------
__global__ void k_offsets(const int* __restrict__ counts,
                          int* __restrict__ offsets, int* __restrict__ cursor) {
    if (threadIdx.x == 0) {
        int acc = 0;
        for (int c = 0; c < NCLS; ++c) { offsets[c] = acc; cursor[c] = acc; acc += counts[c]; }
    }
}

// ---- k2: class-sorted row-index array -------------------------------------
__global__ __launch_bounds__(256) void k_idx(
    const int* __restrict__ labels, int nrows, int vfac,
    int* __restrict__ cursor, int* __restrict__ idx)
{
    __shared__ int lcnt[NCLS], lbase[NCLS];
    int t = threadIdx.x;
    int row = blockIdx.x * SEG + t;
    if (t < NCLS) lcnt[t] = 0;
    __syncthreads();
    int c = 0, rk = 0;
    bool ok = (row < nrows);
    if (ok) {
        c = labels[row / vfac] & 7;
        rk = atomicAdd(&lcnt[c], 1);
    }
    __syncthreads();
    if (t < NCLS) lbase[t] = lcnt[t] ? atomicAdd(&cursor[t], lcnt[t]) : 0;
    __syncthreads();
    if (ok) idx[lbase[c] + rk] = row;
}

// ---- k3: per-(chunk, col-quarter) Gram via MFMA ---------------------------
// WG = 512 threads, 8 waves as 4x2: wave computes 64 rows x 32 cols of the
// 256x64 output quarter. acc = 4x2 fragments = 32 regs/thread.
// LDS K-tile (64 k-rows x 256 feature-cols), single buffer, transposed:
//   quad (ccol, k/4) at byte ccol*128 + ((k&~3)*2 ^ ((ccol&7)<<4))
// Staging thread (kblk=t&15, cblk=t>>4) owns k-rows kblk*4..+3, cols
// cblk*8..+7. Validated conflict-free (rounds 3-8: SQ_LDS_BANK_CONFLICT=0).
__global__ __launch_bounds__(512) void k_gram_g(
    const float* __restrict__ X, const int* __restrict__ idx,
    const int* __restrict__ counts, const int* __restrict__ offsets,
    float* __restrict__ part, float* __restrict__ csums)
{
    __shared__ __align__(16) unsigned char lds[64 * 256 * 2];   // 32 KB
    __shared__ int lidx[CHUNK];                                  // 4 KB

    int t = threadIdx.x;
    int lane = t & 63;
    int w = t >> 6;
    int wrow = w >> 1;          // 0..3 : 64-row band
    int wcol = w & 1;           // 0..1 : 32-col band within the quarter
    int kblk = t & 15;
    int cblk = t >> 4;

    int nch[NCLS], ofch[NCLS];
    int T = 0;
    for (int c = 0; c < NCLS; ++c) {
        int n = counts[c];
        nch[c] = (n + CHUNK - 1) / CHUNK;
        ofch[c] = T;
        T += nch[c];
    }

    const f32x4 zf = {0.f, 0.f, 0.f, 0.f};

    for (int wk = blockIdx.x; wk < 4 * T; wk += gridDim.x) {
        int item = wk >> 2;
        int quarter = wk & 3;
        int c = 0;
        while (c < NCLS - 1 && item >= ofch[c + 1]) ++c;
        int chunk = item - ofch[c];
        int base = offsets[c] + chunk * CHUNK;
        int rows = min(CHUNK, counts[c] - chunk * CHUNK);
        int ntiles = (rows + 63) >> 6;

        // stage the chunk's row ids into LDS (coalesced, clamped)
        for (int i = t; i < CHUNK; i += 512)
            lidx[i] = idx[base + min(i, rows - 1)];

        f32x4 acc[4][2];
        #pragma unroll
        for (int i = 0; i < 4; ++i)
            #pragma unroll
            for (int j = 0; j < 2; ++j)
                #pragma unroll
                for (int r = 0; r < 4; ++r) acc[i][j][r] = 0.f;
        float sumv[8];
        #pragma unroll
        for (int q = 0; q < 8; ++q) sumv[q] = 0.f;

        __syncthreads();   // lidx visible (also orders prior-item LDS reuse)

        for (int kt = 0; kt < ntiles; ++kt) {
            // gather + convert + pack (transient regs; TLP hides latency)
            uint4 R[4];
            #pragma unroll
            for (int j = 0; j < 4; ++j) {
                int r = kt * 64 + kblk * 4 + j;
                int rid = lidx[r];
                const float* rp = X + ((size_t)rid << 8) + cblk * 8;
                f32x4 fa = *(const f32x4*)rp;
                f32x4 fb = *(const f32x4*)(rp + 4);
                if (r >= rows) { fa = zf; fb = zf; }
                #pragma unroll
                for (int q = 0; q < 4; ++q) { sumv[q] += fa[q]; sumv[4 + q] += fb[q]; }
                unsigned int w0 = (unsigned int)f2bf(fa[0]) | ((unsigned int)f2bf(fa[1]) << 16);
                unsigned int w1 = (unsigned int)f2bf(fa[2]) | ((unsigned int)f2bf(fa[3]) << 16);
                unsigned int w2 = (unsigned int)f2bf(fb[0]) | ((unsigned int)f2bf(fb[1]) << 16);
                unsigned int w3 = (unsigned int)f2bf(fb[2]) | ((unsigned int)f2bf(fb[3]) << 16);
                R[j] = make_uint4(w0, w1, w2, w3);
            }
            __syncthreads();           // previous tile's LDS reads done
            // R -> LDS transposed (4 k-rows packed per 8B write)
            #pragma unroll
            for (int cc = 0; cc < 8; ++cc) {
                int wd = cc >> 1;
                int sh = (cc & 1) * 16;
                unsigned int e0 = (((const unsigned int*)&R[0])[wd] >> sh) & 0xffffu;
                unsigned int e1 = (((const unsigned int*)&R[1])[wd] >> sh) & 0xffffu;
                unsigned int e2 = (((const unsigned int*)&R[2])[wd] >> sh) & 0xffffu;
                unsigned int e3 = (((const unsigned int*)&R[3])[wd] >> sh) & 0xffffu;
                int ccol = cblk * 8 + cc;
                int byt = ccol * 128 + ((kblk * 8) ^ (cc << 4));
                *(uint2*)(lds + byt) = make_uint2(e0 | (e1 << 16), e2 | (e3 << 16));
            }
            __syncthreads();           // staging visible
            // MFMA: 2 k-steps of 32
            #pragma unroll
            for (int ks = 0; ks < 2; ++ks) {
                int kb2 = ks * 64 + ((lane >> 4) << 4);
                int swz = (lane & 7) << 4;
                bf16x8 bfr[2];
                #pragma unroll
                for (int tj = 0; tj < 2; ++tj) {
                    int ccol = quarter * 64 + wcol * 32 + tj * 16 + (lane & 15);
                    bfr[tj] = __builtin_bit_cast(bf16x8,
                        *(const uint4*)(lds + ccol * 128 + (kb2 ^ swz)));
                }
                #pragma unroll
                for (int ti = 0; ti < 4; ++ti) {
                    int ccol = wrow * 64 + ti * 16 + (lane & 15);
                    bf16x8 af = __builtin_bit_cast(bf16x8,
                        *(const uint4*)(lds + ccol * 128 + (kb2 ^ swz)));
                    #pragma unroll
                    for (int tj = 0; tj < 2; ++tj)
                        acc[ti][tj] = __builtin_amdgcn_mfma_f32_16x16x32_bf16(
                            af, bfr[tj], acc[ti][tj], 0, 0, 0);
                }
            }
        }

        // flush: plain stores (C/D: col=lane&15, row=(lane>>4)*4+r)
        float* dst = part + (size_t)item * (D * D);
        #pragma unroll
        for (int ti = 0; ti < 4; ++ti) {
            int row0 = wrow * 64 + ti * 16 + ((lane >> 4) << 2);
            #pragma unroll
            for (int tj = 0; tj < 2; ++tj) {
                int col = quarter * 64 + wcol * 32 + tj * 16 + (lane & 15);
                #pragma unroll
                for (int r = 0; r < 4; ++r)
                    dst[(row0 + r) * D + col] = acc[ti][tj][r];
            }
        }

        // per-chunk column sums (all quarters compute; quarter 0 writes)
        #pragma unroll
        for (int s = 1; s < 16; s <<= 1)
            #pragma unroll
            for (int q = 0; q < 8; ++q)
                sumv[q] += __shfl_xor(sumv[q], s, 64);
        if (quarter == 0 && (t & 15) == 0) {
            float* cs = csums + (size_t)item * D + cblk * 8;
            #pragma unroll
            for (int q = 0; q < 8; ++q) cs[q] = sumv[q];
        }
        __syncthreads();   // protect LDS (lidx/tile) before next work-item
    }
}

// ---- k4: reduce per-chunk column sums -> per-class sums -------------------
__global__ __launch_bounds__(256) void k_gsum(
    const float* __restrict__ csums, const int* __restrict__ counts,
    float* __restrict__ gsums)
{
    int c = blockIdx.x;
    int i = threadIdx.x;
    int of = 0;
    for (int cc = 0; cc < c; ++cc) of += (counts[cc] + CHUNK - 1) / CHUNK;
    int nc = (counts[c] + CHUNK - 1) / CHUNK;
    float s = 0.f;
    for (int q = 0; q < nc; ++q) s += csums[(size_t)(of + q) * D + i];
    gsums[c * D + i] = s;
}

// ---- k5: loss epilogue from per-chunk partial Grams -----------------------
__global__ __launch_bounds__(256) void k_loss(
    const float* __restrict__ part, const float* __restrict__ gsums,
    const int* __restrict__ counts, float* __restrict__ out)
{
    __shared__ float red[256];
    int t = threadIdx.x;
    int nch[NCLS], ofch[NCLS];
    int T = 0;
    for (int c = 0; c < NCLS; ++c) {
        int n = counts[c];
        nch[c] = (n + CHUNK - 1) / CHUNK;
        ofch[c] = T;
        T += nch[c];
    }
    float local = 0.f;
    const int total = NCLS * D * D;
    for (int idx = blockIdx.x * blockDim.x + t; idx < total; idx += gridDim.x * blockDim.x) {
        int c = idx >> 16;
        int ij = idx & 0xffff;
        int i = ij >> 8, j = ij & 255;
        const float* p = part + (size_t)ofch[c] * (D * D) + ij;
        float s = 0.f;
        for (int q = 0; q < nch[c]; ++q) s += p[(size_t)q * (D * D)];
        float n  = (float)counts[c];
        float mi = gsums[c * D + i] / n;
        float mj = gsums[c * D + j] / n;
        float cov = (s - n * mi * mj) / (n - 1.f);
        float contrib;
        if (i == j) {
            float sd = sqrtf(cov + EPSF);
            contrib = fmaxf(1.f - sd, 0.f) * (1.f / (float)D);
        } else {
            contrib = cov * cov * (1.f / (float)D);
        }
        local += contrib;
    }
    red[t] = local;
    __syncthreads();
    for (int s = 128; s > 0; s >>= 1) {
        if (t < s) red[t] += red[t + s];
        __syncthreads();
    }
    if (t == 0) atomicAdd(out, red[0]);
}

// ---------------------------------------------------------------------------
extern "C" void kernel_launch(void* const* d_in, const int* in_sizes, int n_in,
                              void* d_out, int out_size, void* d_ws, size_t ws_size,
                              hipStream_t stream)
{
    const float* X      = (const float*)d_in[0];
    const int*   labels = (const int*)d_in[1];
    int nfeat = in_sizes[0];
    int nlab  = in_sizes[1];
    int nrows = nfeat / D;            // 131072
    int vfac  = nrows / nlab;         // 2 views per sample

    char* ws = (char*)d_ws;
    size_t off_idx   = 0;
    size_t sz_idx    = (size_t)nrows * 4;                 // 512 KB
    size_t off_part  = (off_idx + sz_idx + 255) & ~(size_t)255;
    size_t sz_part   = (size_t)TMAX * D * D * 4;          // 37.7 MB
    size_t off_cs    = (off_part + sz_part + 255) & ~(size_t)255;
    size_t sz_cs     = (size_t)TMAX * D * 4;              // 147 KB
    size_t off_gs    = (off_cs + sz_cs + 255) & ~(size_t)255;
    size_t sz_gs     = (size_t)NCLS * D * 4;              // 8 KB
    size_t off_cnt   = (off_gs + sz_gs + 255) & ~(size_t)255;
    size_t off_ofs   = off_cnt + 64;
    size_t off_cur   = off_ofs + 64;

    int*   idx     = (int*)(ws + off_idx);
    float* part    = (float*)(ws + off_part);
    float* csums   = (float*)(ws + off_cs);
    float* gsums   = (float*)(ws + off_gs);
    int*   counts  = (int*)(ws + off_cnt);
    int*   offsets = (int*)(ws + off_ofs);
    int*   cursor  = (int*)(ws + off_cur);

    hipMemsetAsync(counts, 0, 64, stream);
    hipMemsetAsync(d_out, 0, (size_t)out_size * sizeof(float), stream);

    k_hist<<<64, 256, 0, stream>>>(labels, nlab, vfac, counts);
    k_offsets<<<1, 64, 0, stream>>>(counts, offsets, cursor);
    k_idx<<<(nrows + SEG - 1) / SEG, SEG, 0, stream>>>(labels, nrows, vfac, cursor, idx);
    k_gram_g<<<4 * TMAX, 512, 0, stream>>>(X, idx, counts, offsets, part, csums);
    k_gsum<<<NCLS, 256, 0, stream>>>(csums, counts, gsums);
    k_loss<<<512, 256, 0, stream>>>(part, gsums, counts, (float*)d_out);
}

// Round 10
// 136.546 us; speedup vs baseline: 1.1856x; 1.1856x over previous
//
#include <hip/hip_runtime.h>
#include <stdint.h>

// ---------------------------------------------------------------------------
// VarianceMaximizationCovarianceMinimizationLoss on MI355X
//   features [65536,2,256] fp32, labels [65536] int32 -> scalar fp32 loss
// Round 10: round-8 branchless dbuf pipeline + ROW-split for TLP.
//   CHUNK 512 -> T<=263 items, grid ~526 (2.05 WG/CU), 2-way col halves
//   (round-8-proven FETCH dedup). Partial Gram slabs in BF16 so the part
//   buffer (34.6 MB) stays inside the proven 38.4 MB ws budget.
// ---------------------------------------------------------------------------

#define NCLS  8
#define D     256
#define CHUNK 512
#define SEG   256
#define EPSF  1e-4f
// sum_c ceil(n_c/CHUNK) <= nrows/CHUNK + NCLS-1 = 256+7 = 263
#define TMAX  264

typedef __bf16 bf16x8 __attribute__((ext_vector_type(8)));
typedef float  f32x4  __attribute__((ext_vector_type(4)));

__device__ __forceinline__ unsigned short f2bf(float f) {
    unsigned int x = __float_as_uint(f);
    x += 0x7fffu + ((x >> 16) & 1u);      // round-to-nearest-even
    return (unsigned short)(x >> 16);
}
__device__ __forceinline__ float bf2f(unsigned short u) {
    unsigned int x = ((unsigned int)u) << 16;
    return __uint_as_float(x);
}

// ---- k1a: histogram of row counts per class -------------------------------
__global__ void k_hist(const int* __restrict__ labels, int nlab, int vfac,
                       int* __restrict__ counts) {
    __shared__ int lc[NCLS];
    int t = threadIdx.x;
    if (t < NCLS) lc[t] = 0;
    __syncthreads();
    for (int i = blockIdx.x * blockDim.x + t; i < nlab; i += gridDim.x * blockDim.x)
        atomicAdd(&lc[labels[i] & 7], vfac);
    __syncthreads();
    if (t < NCLS && lc[t]) atomicAdd(&counts[t], lc[t]);
}

// ---- k1b: offsets + cursors ----------------------------------------------
__global__ void k_offsets(const int* __restrict__ counts,
                          int* __restrict__ offsets, int* __restrict__ cursor) {
    if (threadIdx.x == 0) {
        int acc = 0;
        for (int c = 0; c < NCLS; ++c) { offsets[c] = acc; cursor[c] = acc; acc += counts[c]; }
    }
}

// ---- k2: class-sorted row-index array -------------------------------------
__global__ __launch_bounds__(256) void k_idx(
    const int* __restrict__ labels, int nrows, int vfac,
    int* __restrict__ cursor, int* __restrict__ idx)
{
    __shared__ int lcnt[NCLS], lbase[NCLS];
    int t = threadIdx.x;
    int row = blockIdx.x * SEG + t;
    if (t < NCLS) lcnt[t] = 0;
    __syncthreads();
    int c = 0, rk = 0;
    bool ok = (row < nrows);
    if (ok) {
        c = labels[row / vfac] & 7;
        rk = atomicAdd(&lcnt[c], 1);
    }
    __syncthreads();
    if (t < NCLS) lbase[t] = lcnt[t] ? atomicAdd(&cursor[t], lcnt[t]) : 0;
    __syncthreads();
    if (ok) idx[lbase[c] + rk] = row;
}

// ---- k3: per-(chunk, col-half) Gram, branch-free pipelined gather ---------
// WG = 512 threads, 8 waves as 4x2: wave computes 64 rows x 64 cols of the
// 256x128 output half. acc = 4x4 fragments = 64 regs/thread.
// LDS K-tile (64 k-rows x 256 feature-cols), double-buffered, transposed:
//   quad (ccol, k/4) at byte buf*32768 + ccol*128 + ((k&~3)*2 ^ ((ccol&7)<<4))
// Staging thread (kblk=t&15, cblk=t>>4) owns k-rows kblk*4..+3, cols
// cblk*8..+7. Validated conflict-free (rounds 3-9: SQ_LDS_BANK_CONFLICT=0).
__global__ __launch_bounds__(512) void k_gram_g(
    const float* __restrict__ X, const int* __restrict__ idx,
    const int* __restrict__ counts, const int* __restrict__ offsets,
    unsigned short* __restrict__ part, float* __restrict__ csums)
{
    __shared__ __align__(16) unsigned char lds[2][64 * 256 * 2];   // 64 KB

    int t = threadIdx.x;
    int lane = t & 63;
    int w = t >> 6;
    int wrow = w >> 1;          // 0..3 : 64-row band
    int wcol = w & 1;           // 0..1 : 64-col band within the half
    int kblk = t & 15;
    int cblk = t >> 4;

    int nch[NCLS], ofch[NCLS];
    int T = 0;
    for (int c = 0; c < NCLS; ++c) {
        int n = counts[c];
        nch[c] = (n + CHUNK - 1) / CHUNK;
        ofch[c] = T;
        T += nch[c];
    }

    const f32x4 zf = {0.f, 0.f, 0.f, 0.f};

    for (int wk = blockIdx.x; wk < 2 * T; wk += gridDim.x) {
        int item = wk >> 1;
        int half = wk & 1;
        int c = 0;
        while (c < NCLS - 1 && item >= ofch[c + 1]) ++c;
        int chunk = item - ofch[c];
        int base = offsets[c] + chunk * CHUNK;
        int rows = min(CHUNK, counts[c] - chunk * CHUNK);
        int ntiles = (rows + 63) >> 6;

        f32x4 acc[4][4];
        #pragma unroll
        for (int i = 0; i < 4; ++i)
            #pragma unroll
            for (int j = 0; j < 4; ++j)
                #pragma unroll
                for (int r = 0; r < 4; ++r) acc[i][j][r] = 0.f;
        float sumv[8];
        #pragma unroll
        for (int q = 0; q < 8; ++q) sumv[q] = 0.f;

        f32x4 fa[4], fb[4];
        uint4 R[4];
        int idn[4];

        // ================= prologue: stage tile 0 into buf0 =================
        #pragma unroll
        for (int j = 0; j < 4; ++j) {
            int r = kblk * 4 + j;
            int rid = idx[base + min(r, rows - 1)];
            const float* rp = X + ((size_t)rid << 8) + cblk * 8;
            fa[j] = *(const f32x4*)rp;
            fb[j] = *(const f32x4*)(rp + 4);
            if (r >= rows) { fa[j] = zf; fb[j] = zf; }
        }
        #pragma unroll
        for (int j = 0; j < 4; ++j) {
            int r = 64 + kblk * 4 + j;
            idn[j] = idx[base + min(r, rows - 1)];
        }
        #pragma unroll
        for (int j = 0; j < 4; ++j) {
            #pragma unroll
            for (int q = 0; q < 4; ++q) { sumv[q] += fa[j][q]; sumv[4 + q] += fb[j][q]; }
            unsigned int w0 = (unsigned int)f2bf(fa[j][0]) | ((unsigned int)f2bf(fa[j][1]) << 16);
            unsigned int w1 = (unsigned int)f2bf(fa[j][2]) | ((unsigned int)f2bf(fa[j][3]) << 16);
            unsigned int w2 = (unsigned int)f2bf(fb[j][0]) | ((unsigned int)f2bf(fb[j][1]) << 16);
            unsigned int w3 = (unsigned int)f2bf(fb[j][2]) | ((unsigned int)f2bf(fb[j][3]) << 16);
            R[j] = make_uint4(w0, w1, w2, w3);
        }
        #pragma unroll
        for (int cc = 0; cc < 8; ++cc) {
            int wd = cc >> 1;
            int sh = (cc & 1) * 16;
            unsigned int e0 = (((const unsigned int*)&R[0])[wd] >> sh) & 0xffffu;
            unsigned int e1 = (((const unsigned int*)&R[1])[wd] >> sh) & 0xffffu;
            unsigned int e2 = (((const unsigned int*)&R[2])[wd] >> sh) & 0xffffu;
            unsigned int e3 = (((const unsigned int*)&R[3])[wd] >> sh) & 0xffffu;
            int ccol = cblk * 8 + cc;
            int byt = ccol * 128 + ((kblk * 8) ^ (cc << 4));
            *(uint2*)(&lds[0][0] + byt) = make_uint2(e0 | (e1 << 16), e2 | (e3 << 16));
        }
        __syncthreads();

        // ================= main loop: branch-free A/B/C pipeline ============
        int ntm1 = ntiles - 1;
        for (int kt = 0; kt < ntm1; ++kt) {
            int cur = kt & 1;
            // --- A: issue tile kt+1 loads (unconditional, clamped ids) ---
            #pragma unroll
            for (int j = 0; j < 4; ++j) {
                const float* rp = X + ((size_t)idn[j] << 8) + cblk * 8;
                fa[j] = *(const f32x4*)rp;
                fb[j] = *(const f32x4*)(rp + 4);
            }
            int idnn[4];
            #pragma unroll
            for (int j = 0; j < 4; ++j) {
                int r = (kt + 2) * 64 + kblk * 4 + j;
                idnn[j] = idx[base + min(r, rows - 1)];
            }
            __builtin_amdgcn_sched_barrier(0);   // loads issue before MFMA

            // --- B: MFMA on buf[cur] ---
            {
                const unsigned char* lb = &lds[0][0] + cur * 32768;
                #pragma unroll
                for (int ks = 0; ks < 2; ++ks) {
                    int kb2 = ks * 64 + ((lane >> 4) << 4);
                    int swz = (lane & 7) << 4;
                    bf16x8 bfr[4];
                    #pragma unroll
                    for (int tj = 0; tj < 4; ++tj) {
                        int ccol = half * 128 + wcol * 64 + tj * 16 + (lane & 15);
                        bfr[tj] = __builtin_bit_cast(bf16x8,
                            *(const uint4*)(lb + ccol * 128 + (kb2 ^ swz)));
                    }
                    #pragma unroll
                    for (int ti = 0; ti < 4; ++ti) {
                        int ccol = wrow * 64 + ti * 16 + (lane & 15);
                        bf16x8 af = __builtin_bit_cast(bf16x8,
                            *(const uint4*)(lb + ccol * 128 + (kb2 ^ swz)));
                        #pragma unroll
                        for (int tj = 0; tj < 4; ++tj)
                            acc[ti][tj] = __builtin_amdgcn_mfma_f32_16x16x32_bf16(
                                af, bfr[tj], acc[ti][tj], 0, 0, 0);
                    }
                }
            }
            __builtin_amdgcn_sched_barrier(0);   // consume stays after MFMA

            // --- C: zero-select + sums + pack + ds_write buf[cur^1] ---
            #pragma unroll
            for (int j = 0; j < 4; ++j) {
                int r = (kt + 1) * 64 + kblk * 4 + j;
                if (r >= rows) { fa[j] = zf; fb[j] = zf; }
                #pragma unroll
                for (int q = 0; q < 4; ++q) { sumv[q] += fa[j][q]; sumv[4 + q] += fb[j][q]; }
                unsigned int w0 = (unsigned int)f2bf(fa[j][0]) | ((unsigned int)f2bf(fa[j][1]) << 16);
                unsigned int w1 = (unsigned int)f2bf(fa[j][2]) | ((unsigned int)f2bf(fa[j][3]) << 16);
                unsigned int w2 = (unsigned int)f2bf(fb[j][0]) | ((unsigned int)f2bf(fb[j][1]) << 16);
                unsigned int w3 = (unsigned int)f2bf(fb[j][2]) | ((unsigned int)f2bf(fb[j][3]) << 16);
                R[j] = make_uint4(w0, w1, w2, w3);
            }
            {
                unsigned char* wb = &lds[0][0] + (cur ^ 1) * 32768;
                #pragma unroll
                for (int cc = 0; cc < 8; ++cc) {
                    int wd = cc >> 1;
                    int sh = (cc & 1) * 16;
                    unsigned int e0 = (((const unsigned int*)&R[0])[wd] >> sh) & 0xffffu;
                    unsigned int e1 = (((const unsigned int*)&R[1])[wd] >> sh) & 0xffffu;
                    unsigned int e2 = (((const unsigned int*)&R[2])[wd] >> sh) & 0xffffu;
                    unsigned int e3 = (((const unsigned int*)&R[3])[wd] >> sh) & 0xffffu;
                    int ccol = cblk * 8 + cc;
                    int byt = ccol * 128 + ((kblk * 8) ^ (cc << 4));
                    *(uint2*)(wb + byt) = make_uint2(e0 | (e1 << 16), e2 | (e3 << 16));
                }
            }
            #pragma unroll
            for (int j = 0; j < 4; ++j) idn[j] = idnn[j];
            __syncthreads();
        }

        // ================= epilogue: MFMA last tile =========================
        {
            const unsigned char* lb = &lds[0][0] + (ntm1 & 1) * 32768;
            #pragma unroll
            for (int ks = 0; ks < 2; ++ks) {
                int kb2 = ks * 64 + ((lane >> 4) << 4);
                int swz = (lane & 7) << 4;
                bf16x8 bfr[4];
                #pragma unroll
                for (int tj = 0; tj < 4; ++tj) {
                    int ccol = half * 128 + wcol * 64 + tj * 16 + (lane & 15);
                    bfr[tj] = __builtin_bit_cast(bf16x8,
                        *(const uint4*)(lb + ccol * 128 + (kb2 ^ swz)));
                }
                #pragma unroll
                for (int ti = 0; ti < 4; ++ti) {
                    int ccol = wrow * 64 + ti * 16 + (lane & 15);
                    bf16x8 af = __builtin_bit_cast(bf16x8,
                        *(const uint4*)(lb + ccol * 128 + (kb2 ^ swz)));
                    #pragma unroll
                    for (int tj = 0; tj < 4; ++tj)
                        acc[ti][tj] = __builtin_amdgcn_mfma_f32_16x16x32_bf16(
                            af, bfr[tj], acc[ti][tj], 0, 0, 0);
                }
            }
        }

        // flush: bf16 plain stores (C/D: col=lane&15, row=(lane>>4)*4+r)
        unsigned short* dst = part + (size_t)item * (D * D);
        #pragma unroll
        for (int ti = 0; ti < 4; ++ti) {
            int row0 = wrow * 64 + ti * 16 + ((lane >> 4) << 2);
            #pragma unroll
            for (int tj = 0; tj < 4; ++tj) {
                int col = half * 128 + wcol * 64 + tj * 16 + (lane & 15);
                #pragma unroll
                for (int r = 0; r < 4; ++r)
                    dst[(row0 + r) * D + col] = f2bf(acc[ti][tj][r]);
            }
        }

        // per-chunk column sums (both halves compute; half 0 writes)
        #pragma unroll
        for (int s = 1; s < 16; s <<= 1)
            #pragma unroll
            for (int q = 0; q < 8; ++q)
                sumv[q] += __shfl_xor(sumv[q], s, 64);
        if (half == 0 && (t & 15) == 0) {
            float* cs = csums + (size_t)item * D + cblk * 8;
            #pragma unroll
            for (int q = 0; q < 8; ++q) cs[q] = sumv[q];
        }
        __syncthreads();   // protect LDS before next work-item's prologue
    }
}

// ---- k4: reduce per-chunk column sums -> per-class sums -------------------
__global__ __launch_bounds__(256) void k_gsum(
    const float* __restrict__ csums, const int* __restrict__ counts,
    float* __restrict__ gsums)
{
    int c = blockIdx.x;
    int i = threadIdx.x;
    int of = 0;
    for (int cc = 0; cc < c; ++cc) of += (counts[cc] + CHUNK - 1) / CHUNK;
    int nc = (counts[c] + CHUNK - 1) / CHUNK;
    float s = 0.f;
    for (int q = 0; q < nc; ++q) s += csums[(size_t)(of + q) * D + i];
    gsums[c * D + i] = s;
}

// ---- k5: loss epilogue from bf16 per-chunk partial Grams ------------------
__global__ __launch_bounds__(256) void k_loss(
    const unsigned short* __restrict__ part, const float* __restrict__ gsums,
    const int* __restrict__ counts, float* __restrict__ out)
{
    __shared__ float red[256];
    int t = threadIdx.x;
    int nch[NCLS], ofch[NCLS];
    int T = 0;
    for (int c = 0; c < NCLS; ++c) {
        int n = counts[c];
        nch[c] = (n + CHUNK - 1) / CHUNK;
        ofch[c] = T;
        T += nch[c];
    }
    float local = 0.f;
    const int total = NCLS * D * D;
    for (int idx = blockIdx.x * blockDim.x + t; idx < total; idx += gridDim.x * blockDim.x) {
        int c = idx >> 16;
        int ij = idx & 0xffff;
        int i = ij >> 8, j = ij & 255;
        const unsigned short* p = part + (size_t)ofch[c] * (D * D) + ij;
        float s = 0.f;
        for (int q = 0; q < nch[c]; ++q) s += bf2f(p[(size_t)q * (D * D)]);
        float n  = (float)counts[c];
        float mi = gsums[c * D + i] / n;
        float mj = gsums[c * D + j] / n;
        float cov = (s - n * mi * mj) / (n - 1.f);
        float contrib;
        if (i == j) {
            float sd = sqrtf(cov + EPSF);
            contrib = fmaxf(1.f - sd, 0.f) * (1.f / (float)D);
        } else {
            contrib = cov * cov * (1.f / (float)D);
        }
        local += contrib;
    }
    red[t] = local;
    __syncthreads();
    for (int s = 128; s > 0; s >>= 1) {
        if (t < s) red[t] += red[t + s];
        __syncthreads();
    }
    if (t == 0) atomicAdd(out, red[0]);
}

// ---------------------------------------------------------------------------
extern "C" void kernel_launch(void* const* d_in, const int* in_sizes, int n_in,
                              void* d_out, int out_size, void* d_ws, size_t ws_size,
                              hipStream_t stream)
{
    const float* X      = (const float*)d_in[0];
    const int*   labels = (const int*)d_in[1];
    int nfeat = in_sizes[0];
    int nlab  = in_sizes[1];
    int nrows = nfeat / D;            // 131072
    int vfac  = nrows / nlab;         // 2 views per sample

    char* ws = (char*)d_ws;
    size_t off_idx   = 0;
    size_t sz_idx    = (size_t)nrows * 4;                 // 512 KB
    size_t off_part  = (off_idx + sz_idx + 255) & ~(size_t)255;
    size_t sz_part   = (size_t)TMAX * D * D * 2;          // 34.6 MB bf16
    size_t off_cs    = (off_part + sz_part + 255) & ~(size_t)255;
    size_t sz_cs     = (size_t)TMAX * D * 4;              // 270 KB
    size_t off_gs    = (off_cs + sz_cs + 255) & ~(size_t)255;
    size_t sz_gs     = (size_t)NCLS * D * 4;              // 8 KB
    size_t off_cnt   = (off_gs + sz_gs + 255) & ~(size_t)255;
    size_t off_ofs   = off_cnt + 64;
    size_t off_cur   = off_ofs + 64;

    int*            idx     = (int*)(ws + off_idx);
    unsigned short* part    = (unsigned short*)(ws + off_part);
    float*          csums   = (float*)(ws + off_cs);
    float*          gsums   = (float*)(ws + off_gs);
    int*            counts  = (int*)(ws + off_cnt);
    int*            offsets = (int*)(ws + off_ofs);
    int*            cursor  = (int*)(ws + off_cur);

    hipMemsetAsync(counts, 0, 64, stream);
    hipMemsetAsync(d_out, 0, (size_t)out_size * sizeof(float), stream);

    k_hist<<<64, 256, 0, stream>>>(labels, nlab, vfac, counts);
    k_offsets<<<1, 64, 0, stream>>>(counts, offsets, cursor);
    k_idx<<<(nrows + SEG - 1) / SEG, SEG, 0, stream>>>(labels, nrows, vfac, cursor, idx);
    k_gram_g<<<2 * TMAX, 512, 0, stream>>>(X, idx, counts, offsets, part, csums);
    k_gsum<<<NCLS, 256, 0, stream>>>(csums, counts, gsums);
    k_loss<<<512, 256, 0, stream>>>(part, gsums, counts, (float*)d_out);
}

// Round 11
// 134.557 us; speedup vs baseline: 1.2031x; 1.0148x over previous
//
#include <hip/hip_runtime.h>
#include <stdint.h>

// ---------------------------------------------------------------------------
// VarianceMaximizationCovarianceMinimizationLoss on MI355X
//   features [65536,2,256] fp32, labels [65536] int32 -> scalar fp32 loss
// Round 11: 4-wave WGs + quadrant decomposition for real co-residency.
//   True per-thread regs = 104 VGPR + 64 AGPR = 168 -> 8-12 waves/CU; an
//   8-wave WG monopolizes the CU (rounds 8/10: occupancy stuck 19%).
//   4-wave WGs (2x2 waves, 128x128 output quadrant, acc still 64 AGPR)
//   let 2-3 INDEPENDENT WGs interleave per CU. Symmetry: only quadrants
//   (0,0),(1,1),(0,1) computed; k_loss weights (0,1) twice.
// ---------------------------------------------------------------------------

#define NCLS  8
#define D     256
#define CHUNK 512
#define SEG   256
#define EPSF  1e-4f
// sum_c ceil(n_c/CHUNK) <= nrows/CHUNK + NCLS-1 = 256+7 = 263
#define TMAX  264
#define QLEN  16384      // 128*128 slab elements

typedef __bf16 bf16x8 __attribute__((ext_vector_type(8)));
typedef float  f32x4  __attribute__((ext_vector_type(4)));

__device__ __forceinline__ unsigned short f2bf(float f) {
    unsigned int x = __float_as_uint(f);
    x += 0x7fffu + ((x >> 16) & 1u);      // round-to-nearest-even
    return (unsigned short)(x >> 16);
}
__device__ __forceinline__ float bf2f(unsigned short u) {
    return __uint_as_float(((unsigned int)u) << 16);
}
__device__ __forceinline__ uint4 pack8(const f32x4& a, const f32x4& b) {
    return make_uint4(
        (unsigned int)f2bf(a[0]) | ((unsigned int)f2bf(a[1]) << 16),
        (unsigned int)f2bf(a[2]) | ((unsigned int)f2bf(a[3]) << 16),
        (unsigned int)f2bf(b[0]) | ((unsigned int)f2bf(b[1]) << 16),
        (unsigned int)f2bf(b[2]) | ((unsigned int)f2bf(b[3]) << 16));
}
// transposed + XOR-swizzled LDS write of 4 k-rows x 8 cols (validated
// conflict-free rounds 3-10: SQ_LDS_BANK_CONFLICT = 0)
__device__ __forceinline__ void st_tile(unsigned char* lds, const uint4* R,
                                        int kblk, int cblkg) {
    #pragma unroll
    for (int cc = 0; cc < 8; ++cc) {
        int wd = cc >> 1;
        int sh = (cc & 1) * 16;
        unsigned int e0 = (((const unsigned int*)&R[0])[wd] >> sh) & 0xffffu;
        unsigned int e1 = (((const unsigned int*)&R[1])[wd] >> sh) & 0xffffu;
        unsigned int e2 = (((const unsigned int*)&R[2])[wd] >> sh) & 0xffffu;
        unsigned int e3 = (((const unsigned int*)&R[3])[wd] >> sh) & 0xffffu;
        int ccol = cblkg * 8 + cc;
        int byt = ccol * 128 + ((kblk * 8) ^ (cc << 4));
        *(uint2*)(lds + byt) = make_uint2(e0 | (e1 << 16), e2 | (e3 << 16));
    }
}

// ---- k1a: histogram of row counts per class -------------------------------
__global__ void k_hist(const int* __restrict__ labels, int nlab, int vfac,
                       int* __restrict__ counts) {
    __shared__ int lc[NCLS];
    int t = threadIdx.x;
    if (t < NCLS) lc[t] = 0;
    __syncthreads();
    for (int i = blockIdx.x * blockDim.x + t; i < nlab; i += gridDim.x * blockDim.x)
        atomicAdd(&lc[labels[i] & 7], vfac);
    __syncthreads();
    if (t < NCLS && lc[t]) atomicAdd(&counts[t], lc[t]);
}

// ---- k1b: offsets + cursors ----------------------------------------------
__global__ void k_offsets(const int* __restrict__ counts,
                          int* __restrict__ offsets, int* __restrict__ cursor) {
    if (threadIdx.x == 0) {
        int acc = 0;
        for (int c = 0; c < NCLS; ++c) { offsets[c] = acc; cursor[c] = acc; acc += counts[c]; }
    }
}

// ---- k2: class-sorted row-index array -------------------------------------
__global__ __launch_bounds__(256) void k_idx(
    const int* __restrict__ labels, int nrows, int vfac,
    int* __restrict__ cursor, int* __restrict__ idx)
{
    __shared__ int lcnt[NCLS], lbase[NCLS];
    int t = threadIdx.x;
    int row = blockIdx.x * SEG + t;
    if (t < NCLS) lcnt[t] = 0;
    __syncthreads();
    int c = 0, rk = 0;
    bool ok = (row < nrows);
    if (ok) {
        c = labels[row / vfac] & 7;
        rk = atomicAdd(&lcnt[c], 1);
    }
    __syncthreads();
    if (t < NCLS) lbase[t] = lcnt[t] ? atomicAdd(&cursor[t], lcnt[t]) : 0;
    __syncthreads();
    if (ok) idx[lbase[c] + rk] = row;
}

// ---- k3: per-(chunk, quadrant) 128x128 Gram via MFMA ----------------------
// WG = 256 threads, 4 waves as 2x2: wave computes 64x64 -> acc 4x4 frags
// (64 AGPR). Quadrants: q0=(rows 0-127 x cols 0-127), q1=(128-255 x
// 128-255), q2=(0-127 x 128-255). q0/q1 stage 64x128 (16 KB), q2 64x256.
// Staging thread (kblk=t&15, cblk0=t>>4) owns k-rows kblk*4..+3, 8 cols.
__global__ __launch_bounds__(256) void k_gram_g(
    const float* __restrict__ X, const int* __restrict__ idx,
    const int* __restrict__ counts, const int* __restrict__ offsets,
    unsigned short* __restrict__ part, float* __restrict__ csums)
{
    __shared__ __align__(16) unsigned char lds[64 * 256 * 2];   // 32 KB

    int t = threadIdx.x;
    int lane = t & 63;
    int w = t >> 6;             // 0..3
    int wrow = w >> 1, wcol = w & 1;
    int kblk = t & 15;
    int cblk0 = t >> 4;         // 0..15

    int nch[NCLS], ofch[NCLS];
    int T = 0;
    for (int c = 0; c < NCLS; ++c) {
        int n = counts[c];
        nch[c] = (n + CHUNK - 1) / CHUNK;
        ofch[c] = T;
        T += nch[c];
    }

    const f32x4 zf = {0.f, 0.f, 0.f, 0.f};

    for (int wk = blockIdx.x; wk < 3 * T; wk += gridDim.x) {
        int item = wk / 3;
        int q = wk - item * 3;
        int c = 0;
        while (c < NCLS - 1 && item >= ofch[c + 1]) ++c;
        int chunk = item - ofch[c];
        int base = offsets[c] + chunk * CHUNK;
        int rows = min(CHUNK, counts[c] - chunk * CHUNK);
        int ntiles = (rows + 63) >> 6;

        int colb = (q == 1) ? 128 : 0;     // staged global col base (g0)
        bool two = (q == 2);               // stage second 128-col group
        int bbase = two ? 128 : 0;         // B-frag local col base

        f32x4 acc[4][4];
        #pragma unroll
        for (int i = 0; i < 4; ++i)
            #pragma unroll
            for (int j = 0; j < 4; ++j)
                #pragma unroll
                for (int r = 0; r < 4; ++r) acc[i][j][r] = 0.f;
        float sumv[8];
        #pragma unroll
        for (int e = 0; e < 8; ++e) sumv[e] = 0.f;

        for (int kt = 0; kt < ntiles; ++kt) {
            int rid[4];
            #pragma unroll
            for (int j = 0; j < 4; ++j) {
                int r = kt * 64 + kblk * 4 + j;
                rid[j] = idx[base + min(r, rows - 1)];
            }
            // g0: gather 4 rows x 8 cols at colb + cblk0*8
            uint4 R0[4];
            #pragma unroll
            for (int j = 0; j < 4; ++j) {
                int r = kt * 64 + kblk * 4 + j;
                const float* rp = X + ((size_t)rid[j] << 8) + colb + cblk0 * 8;
                f32x4 a = *(const f32x4*)rp;
                f32x4 b = *(const f32x4*)(rp + 4);
                if (r >= rows) { a = zf; b = zf; }
                #pragma unroll
                for (int e = 0; e < 4; ++e) { sumv[e] += a[e]; sumv[4 + e] += b[e]; }
                R0[j] = pack8(a, b);
            }
            // g1 (q2 only): second 128-col group
            uint4 R1[4];
            if (two) {
                #pragma unroll
                for (int j = 0; j < 4; ++j) {
                    int r = kt * 64 + kblk * 4 + j;
                    const float* rp = X + ((size_t)rid[j] << 8) + 128 + cblk0 * 8;
                    f32x4 a = *(const f32x4*)rp;
                    f32x4 b = *(const f32x4*)(rp + 4);
                    if (r >= rows) { a = zf; b = zf; }
                    R1[j] = pack8(a, b);
                }
            }
            __syncthreads();           // previous tile's LDS reads done
            st_tile(lds, R0, kblk, cblk0);
            if (two) st_tile(lds, R1, kblk, cblk0 + 16);
            __syncthreads();           // staging visible
            // MFMA: 2 k-steps of 32
            #pragma unroll
            for (int ks = 0; ks < 2; ++ks) {
                int kb2 = ks * 64 + ((lane >> 4) << 4);
                int swz = (lane & 7) << 4;
                bf16x8 bfr[4];
                #pragma unroll
                for (int tj = 0; tj < 4; ++tj) {
                    int ccol = bbase + wcol * 64 + tj * 16 + (lane & 15);
                    bfr[tj] = __builtin_bit_cast(bf16x8,
                        *(const uint4*)(lds + ccol * 128 + (kb2 ^ swz)));
                }
                #pragma unroll
                for (int ti = 0; ti < 4; ++ti) {
                    int ccol = wrow * 64 + ti * 16 + (lane & 15);
                    bf16x8 af = __builtin_bit_cast(bf16x8,
                        *(const uint4*)(lds + ccol * 128 + (kb2 ^ swz)));
                    #pragma unroll
                    for (int tj = 0; tj < 4; ++tj)
                        acc[ti][tj] = __builtin_amdgcn_mfma_f32_16x16x32_bf16(
                            af, bfr[tj], acc[ti][tj], 0, 0, 0);
                }
            }
        }

        // flush 128x128 bf16 slab (C/D: col=lane&15, row=(lane>>4)*4+r)
        unsigned short* dst = part + (size_t)wk * QLEN;
        #pragma unroll
        for (int ti = 0; ti < 4; ++ti) {
            int row0 = wrow * 64 + ti * 16 + ((lane >> 4) << 2);
            #pragma unroll
            for (int tj = 0; tj < 4; ++tj) {
                int col = wcol * 64 + tj * 16 + (lane & 15);
                #pragma unroll
                for (int r = 0; r < 4; ++r)
                    dst[(row0 + r) * 128 + col] = f2bf(acc[ti][tj][r]);
            }
        }

        // per-chunk column sums for the staged g0 cols (q0: 0-127, q1:
        // 128-255; q2 skips -> no double count). 16-lane-group reduce.
        #pragma unroll
        for (int s = 1; s < 16; s <<= 1)
            #pragma unroll
            for (int e = 0; e < 8; ++e)
                sumv[e] += __shfl_xor(sumv[e], s, 64);
        if (q < 2 && (t & 15) == 0) {
            float* cs = csums + (size_t)item * D + colb + cblk0 * 8;
            #pragma unroll
            for (int e = 0; e < 8; ++e) cs[e] = sumv[e];
        }
        __syncthreads();   // protect LDS before next work-item's staging
    }
}

// ---- k4: reduce per-chunk column sums -> per-class sums -------------------
__global__ __launch_bounds__(256) void k_gsum(
    const float* __restrict__ csums, const int* __restrict__ counts,
    float* __restrict__ gsums)
{
    int c = blockIdx.x;
    int i = threadIdx.x;
    int of = 0;
    for (int cc = 0; cc < c; ++cc) of += (counts[cc] + CHUNK - 1) / CHUNK;
    int nc = (counts[c] + CHUNK - 1) / CHUNK;
    float s = 0.f;
    for (int q = 0; q < nc; ++q) s += csums[(size_t)(of + q) * D + i];
    gsums[c * D + i] = s;
}

// ---- k5: loss epilogue from quadrant bf16 partial Grams -------------------
// cov^2 over full matrix = sum(q0) + sum(q1) + 2*sum(q2); diag in q0/q1.
__global__ __launch_bounds__(256) void k_loss(
    const unsigned short* __restrict__ part, const float* __restrict__ gsums,
    const int* __restrict__ counts, float* __restrict__ out)
{
    __shared__ float red[256];
    int t = threadIdx.x;
    int nch[NCLS], ofch[NCLS];
    int T = 0;
    for (int c = 0; c < NCLS; ++c) {
        int n = counts[c];
        nch[c] = (n + CHUNK - 1) / CHUNK;
        ofch[c] = T;
        T += nch[c];
    }
    float local = 0.f;
    const int total = NCLS * 3 * QLEN;       // 393216
    for (int idx = blockIdx.x * blockDim.x + t; idx < total; idx += gridDim.x * blockDim.x) {
        int c = idx / (3 * QLEN);
        int rem = idx - c * (3 * QLEN);
        int q = rem >> 14;
        int ij = rem & (QLEN - 1);
        int il = ij >> 7, jl = ij & 127;
        int gi = il + ((q == 1) ? 128 : 0);
        int gj = jl + ((q == 0) ? 0 : 128);
        const unsigned short* p = part + ((size_t)(ofch[c] * 3 + q)) * QLEN + ij;
        float s = 0.f;
        for (int k = 0; k < nch[c]; ++k) s += bf2f(p[(size_t)k * 3 * QLEN]);
        float n  = (float)counts[c];
        float mi = gsums[c * D + gi] / n;
        float mj = gsums[c * D + gj] / n;
        float cov = (s - n * mi * mj) / (n - 1.f);
        float contrib;
        if (q == 2) {
            contrib = 2.f * cov * cov * (1.f / (float)D);
        } else if (il == jl) {
            float sd = sqrtf(cov + EPSF);
            contrib = fmaxf(1.f - sd, 0.f) * (1.f / (float)D);
        } else {
            contrib = cov * cov * (1.f / (float)D);
        }
        local += contrib;
    }
    red[t] = local;
    __syncthreads();
    for (int s = 128; s > 0; s >>= 1) {
        if (t < s) red[t] += red[t + s];
        __syncthreads();
    }
    if (t == 0) atomicAdd(out, red[0]);
}

// ---------------------------------------------------------------------------
extern "C" void kernel_launch(void* const* d_in, const int* in_sizes, int n_in,
                              void* d_out, int out_size, void* d_ws, size_t ws_size,
                              hipStream_t stream)
{
    const float* X      = (const float*)d_in[0];
    const int*   labels = (const int*)d_in[1];
    int nfeat = in_sizes[0];
    int nlab  = in_sizes[1];
    int nrows = nfeat / D;            // 131072
    int vfac  = nrows / nlab;         // 2 views per sample

    char* ws = (char*)d_ws;
    size_t off_idx   = 0;
    size_t sz_idx    = (size_t)nrows * 4;                 // 512 KB
    size_t off_part  = (off_idx + sz_idx + 255) & ~(size_t)255;
    size_t sz_part   = (size_t)3 * TMAX * QLEN * 2;       // 25.9 MB bf16
    size_t off_cs    = (off_part + sz_part + 255) & ~(size_t)255;
    size_t sz_cs     = (size_t)TMAX * D * 4;              // 270 KB
    size_t off_gs    = (off_cs + sz_cs + 255) & ~(size_t)255;
    size_t sz_gs     = (size_t)NCLS * D * 4;              // 8 KB
    size_t off_cnt   = (off_gs + sz_gs + 255) & ~(size_t)255;
    size_t off_ofs   = off_cnt + 64;
    size_t off_cur   = off_ofs + 64;

    int*            idx     = (int*)(ws + off_idx);
    unsigned short* part    = (unsigned short*)(ws + off_part);
    float*          csums   = (float*)(ws + off_cs);
    float*          gsums   = (float*)(ws + off_gs);
    int*            counts  = (int*)(ws + off_cnt);
    int*            offsets = (int*)(ws + off_ofs);
    int*            cursor  = (int*)(ws + off_cur);

    hipMemsetAsync(counts, 0, 64, stream);
    hipMemsetAsync(d_out, 0, (size_t)out_size * sizeof(float), stream);

    k_hist<<<64, 256, 0, stream>>>(labels, nlab, vfac, counts);
    k_offsets<<<1, 64, 0, stream>>>(counts, offsets, cursor);
    k_idx<<<(nrows + SEG - 1) / SEG, SEG, 0, stream>>>(labels, nrows, vfac, cursor, idx);
    k_gram_g<<<3 * TMAX, 256, 0, stream>>>(X, idx, counts, offsets, part, csums);
    k_gsum<<<NCLS, 256, 0, stream>>>(csums, counts, gsums);
    k_loss<<<512, 256, 0, stream>>>(part, gsums, counts, (float*)d_out);
}